// Round 11
// baseline (568.152 us; speedup 1.0000x reference)
//
#include <hip/hip_runtime.h>
#include <hip/hip_bf16.h>
#include <cstdint>
#include <cstddef>

#define N_FEAT 512
#define N_HID 64
#define N_CLASS 16
#define N_CLUSTER 32
#define NPART 8          // privatized histogram partitions
#define MFMA_REPS 4      // PROBE: repeat layer-1 GEMM work in-kernel (x4 dur -> top-5)
#define FILL_REPS 3      // PROBE: repeat CSR fill work in-kernel (x3 dur -> top-5)

typedef short short8 __attribute__((ext_vector_type(8)));
typedef float floatx4 __attribute__((ext_vector_type(4)));
typedef unsigned short u16;
typedef unsigned short u16x4 __attribute__((ext_vector_type(4)));

__device__ __forceinline__ short f2bf(float f) {
  __hip_bfloat16 h = __float2bfloat16(f);   // RNE
  return *reinterpret_cast<short*>(&h);
}
__device__ __forceinline__ u16 f2bfu(float f) { return (u16)f2bf(f); }
__device__ __forceinline__ float bf2f(u16 u) {
  return __uint_as_float((unsigned)u << 16);
}

// ---------------- fast zero-fill ----------------
__global__ void k_zeroH(uint4* __restrict__ p, int n16) {
  int i = blockIdx.x * 256 + threadIdx.x;
  if (i < n16) p[i] = make_uint4(0u, 0u, 0u, 0u);
}

// ---------------- packed degree/count histogram: one u64 atomic per edge ----------------
__global__ void k_degcnt2(const int* __restrict__ col, const float* __restrict__ w,
                          unsigned long long* __restrict__ hist, int H, int E) {
  int e = blockIdx.x * 256 + threadIdx.x;
  if (e >= E) return;
  int p = blockIdx.x & (NPART - 1);
  int c = col[e];
  unsigned long long fx = (unsigned long long)__float2uint_rn(w[e] * 16777216.0f);
  atomicAdd(&hist[(size_t)p * H + c], (1ull << 40) | fx);
}

// ---------------- fold partitions + exclusive scan (merged reduce+scan1) ----------------
__global__ __launch_bounds__(256) void k_redscan(
    const unsigned long long* __restrict__ hist, int H,
    float* __restrict__ dinv, int* __restrict__ off,
    int* __restrict__ bsum, int n) {
  __shared__ int sh[256];
  int t = threadIdx.x;
  int i = blockIdx.x * 256 + t;
  int v = 0;
  if (i < n) {
    unsigned long long tot = 0;
    #pragma unroll
    for (int p = 0; p < NPART; ++p) tot += hist[(size_t)p * H + i];
    v = (int)(tot >> 40);
    float wsum = (float)(tot & ((1ull << 40) - 1)) * 5.9604644775390625e-08f; // 2^-24
    dinv[i] = rsqrtf(1.0f + wsum);
  }
  sh[t] = v;
  __syncthreads();
  #pragma unroll
  for (int d = 1; d < 256; d <<= 1) {
    int x = 0;
    if (t >= d) x = sh[t - d];
    __syncthreads();
    if (t >= d) sh[t] += x;
    __syncthreads();
  }
  if (i < n) off[i] = sh[t] - v;
  if (t == 255) bsum[blockIdx.x] = sh[255];
}

__global__ __launch_bounds__(256) void k_scan2(const int* __restrict__ bsum,
                                               int* __restrict__ bsum2, int nb) {
  __shared__ int sh[256];
  int t = threadIdx.x;
  int v = (t < nb) ? bsum[t] : 0;
  sh[t] = v;
  __syncthreads();
  #pragma unroll
  for (int d = 1; d < 256; d <<= 1) {
    int x = 0;
    if (t >= d) x = sh[t - d];
    __syncthreads();
    if (t >= d) sh[t] += x;
    __syncthreads();
  }
  if (t < nb) bsum2[t] = sh[t] - v;
}

// scan fixup + init per-partition cursors (FILL_REPS independent copies for probe)
__global__ void k_scan3_initcur(int* __restrict__ off, const int* __restrict__ bsum2,
                                const unsigned long long* __restrict__ hist, int H,
                                int* __restrict__ cur, int n, int E) {
  int i = blockIdx.x * 256 + threadIdx.x;
  if (i < n) {
    int o = off[i] + bsum2[blockIdx.x];
    off[i] = o;
    #pragma unroll
    for (int rep = 0; rep < FILL_REPS; ++rep) {
      int running = o;
      #pragma unroll
      for (int p = 0; p < NPART; ++p) {
        cur[(size_t)(rep * NPART + p) * H + i] = running;
        running += (int)(hist[(size_t)p * H + i] >> 40);
      }
    }
  }
  if (i == 0) off[n] = E;
}

// ---------------- PROBE fill: repeat the scatter FILL_REPS times ----------------
// Each rep uses its own cursor copy + pairs region; gathers read region 0.
__global__ void k_fill2p(const int* __restrict__ rowi, const int* __restrict__ coli,
                         const float* __restrict__ w, const float* __restrict__ dinv,
                         int* __restrict__ cur, int H,
                         unsigned* __restrict__ pairs, int E) {
  int e = blockIdx.x * 256 + threadIdx.x;
  if (e >= E) return;
  int p = blockIdx.x & (NPART - 1);       // must match k_degcnt2's mapping
  int r = rowi[e], c = coli[e];
  unsigned pk = ((unsigned)r << 16) | (u16)f2bf(dinv[r] * w[e] * dinv[c]);
  #pragma unroll
  for (int rep = 0; rep < FILL_REPS; ++rep) {
    int pos = atomicAdd(&cur[(size_t)(rep * NPART + p) * H + c], 1);
    pairs[(size_t)rep * E + pos] = pk;
  }
}

// ---------------- W[K][64] fp32 -> BF in MFMA-fragment order (bf16) ----------------
__global__ void k_prepBF(const float* __restrict__ W, short* __restrict__ BF, int K) {
  int idx = blockIdx.x * 256 + threadIdx.x;
  int total = (K / 32) * 4 * 64;
  if (idx >= total) return;
  int lane = idx & 63;
  int sj = idx >> 6;
  int j = sj & 3, s = sj >> 2;
  int col = j * 16 + (lane & 15);
  int k0 = s * 32 + ((lane >> 4) << 3);
  short8 v;
  #pragma unroll
  for (int t = 0; t < 8; ++t) v[t] = f2bf(W[(size_t)(k0 + t) * 64 + col]);
  *(short8*)(BF + (size_t)idx * 8) = v;
}

// ---------------- PROBE layer-1 MFMA GEMM: work repeated MFMA_REPS times ----------------
// Identical to round-10 staged kernel, wrapped in a rep loop (acc re-init and
// C re-store each rep keep all work live; reps 2+ run L3-warm = extra diagnostic).
__global__ __launch_bounds__(256, 3) void k_mfma512p(
    const float* __restrict__ A, const short8* __restrict__ BF,
    u16* __restrict__ C, int M) {
  __shared__ float As[2][4096];            // 2 x 64 rows x 64 floats = 32 KB
  const int tid = threadIdx.x;
  const int lane = tid & 63;
  const int wid = tid >> 6;
  const int row0 = blockIdx.x * 64;

  const int srow = tid >> 4;               // 0..15
  const int scol4 = (tid & 15) ^ (srow & 7);
  const float* gsrc[4];
  #pragma unroll
  for (int i = 0; i < 4; ++i) {
    int grow = row0 + i * 16 + srow;
    if (grow >= M) grow = M - 1;
    gsrc[i] = A + (size_t)grow * 512 + scol4 * 4;
  }
  const int ldsoff = tid * 4;

  const int row_r = wid * 16 + (lane & 15);
  const int xr = row_r & 7;
  const int kqb = (lane >> 4) * 2;
  const int srowo = row0 + wid * 16 + (lane >> 4) * 4;
  const int scol = lane & 15;

  float4 st[4];
  short8 pb[2][8];
  floatx4 acc[4];

  #pragma unroll 1
  for (int rep = 0; rep < MFMA_REPS; ++rep) {
    #pragma unroll
    for (int j = 0; j < 4; ++j) acc[j] = (floatx4){0.f, 0.f, 0.f, 0.f};

    // ---- prologue: chunk 0 ----
    #pragma unroll
    for (int i = 0; i < 4; ++i) st[i] = *(const float4*)(gsrc[i]);
    #pragma unroll
    for (int t = 0; t < 8; ++t) pb[0][t] = BF[t * 64 + lane];
    #pragma unroll
    for (int i = 0; i < 4; ++i)
      *(float4*)&As[0][i * 1024 + ldsoff] = st[i];
    __syncthreads();

    #pragma unroll
    for (int c = 0; c < 8; ++c) {
      const int b = c & 1;
      if (c + 1 < 8) {
        #pragma unroll
        for (int i = 0; i < 4; ++i)
          st[i] = *(const float4*)(gsrc[i] + (c + 1) * 64);
        #pragma unroll
        for (int t = 0; t < 8; ++t)
          pb[b ^ 1][t] = BF[((c + 1) * 8 + t) * 64 + lane];
        __builtin_amdgcn_sched_barrier(0);
      }
      const float* rb = &As[b][row_r * 64];
      #pragma unroll
      for (int kq = 0; kq < 2; ++kq) {
        const int k4a = kq * 8 + kqb;
        float4 f0 = *(const float4*)&rb[((k4a)     ^ xr) * 4];
        float4 f1 = *(const float4*)&rb[((k4a + 1) ^ xr) * 4];
        short8 af;
        af[0] = f2bf(f0.x); af[1] = f2bf(f0.y); af[2] = f2bf(f0.z); af[3] = f2bf(f0.w);
        af[4] = f2bf(f1.x); af[5] = f2bf(f1.y); af[6] = f2bf(f1.z); af[7] = f2bf(f1.w);
        acc[0] = __builtin_amdgcn_mfma_f32_16x16x32_bf16(af, pb[b][kq * 4 + 0], acc[0], 0, 0, 0);
        acc[1] = __builtin_amdgcn_mfma_f32_16x16x32_bf16(af, pb[b][kq * 4 + 1], acc[1], 0, 0, 0);
        acc[2] = __builtin_amdgcn_mfma_f32_16x16x32_bf16(af, pb[b][kq * 4 + 2], acc[2], 0, 0, 0);
        acc[3] = __builtin_amdgcn_mfma_f32_16x16x32_bf16(af, pb[b][kq * 4 + 3], acc[3], 0, 0, 0);
      }
      if (c + 1 < 8) {
        #pragma unroll
        for (int i = 0; i < 4; ++i)
          *(float4*)&As[b ^ 1][i * 1024 + ldsoff] = st[i];
        __syncthreads();
      }
    }

    // C-store each rep keeps every rep's work live (no DCE)
    #pragma unroll
    for (int i = 0; i < 4; ++i) {
      int rr = srowo + i;
      if (rr < M) {
        #pragma unroll
        for (int j = 0; j < 4; ++j)
          C[(size_t)rr * 64 + j * 16 + scol] = f2bfu(acc[j][i]);
      }
    }
  }
}

// ---------------- layer-2 MFMA GEMM (K=64, bf16 A, L2-hot): register version ----------------
__global__ __launch_bounds__(64, 4) void k_mfma64(
    const u16* __restrict__ Av, const short8* __restrict__ BF,
    u16* __restrict__ C, int M) {
  const int lane = threadIdx.x & 63;
  const int rbase = blockIdx.x * 16;
  int r = rbase + (lane & 15);
  if (r >= M) r = M - 1;
  const int klo = (lane >> 4) * 8;
  const u16* arow = Av + (size_t)r * 64 + klo;
  const short8* bbase = BF + lane;

  short8 pah[2];
  short8 pb[2][4];
  pah[0] = *(const short8*)(arow);
  pah[1] = *(const short8*)(arow + 32);
  #pragma unroll
  for (int s = 0; s < 2; ++s)
    #pragma unroll
    for (int j = 0; j < 4; ++j)
      pb[s][j] = bbase[(s * 4 + j) * 64];

  floatx4 acc[4];
  #pragma unroll
  for (int j = 0; j < 4; ++j) acc[j] = (floatx4){0.f, 0.f, 0.f, 0.f};

  #pragma unroll
  for (int s = 0; s < 2; ++s) {
    acc[0] = __builtin_amdgcn_mfma_f32_16x16x32_bf16(pah[s], pb[s][0], acc[0], 0, 0, 0);
    acc[1] = __builtin_amdgcn_mfma_f32_16x16x32_bf16(pah[s], pb[s][1], acc[1], 0, 0, 0);
    acc[2] = __builtin_amdgcn_mfma_f32_16x16x32_bf16(pah[s], pb[s][2], acc[2], 0, 0, 0);
    acc[3] = __builtin_amdgcn_mfma_f32_16x16x32_bf16(pah[s], pb[s][3], acc[3], 0, 0, 0);
  }

  const int srow = rbase + (lane >> 4) * 4;
  const int scol = lane & 15;
  #pragma unroll
  for (int i = 0; i < 4; ++i) {
    int rr = srow + i;
    if (rr < M) {
      #pragma unroll
      for (int j = 0; j < 4; ++j)
        C[(size_t)rr * 64 + j * 16 + scol] = f2bfu(acc[j][i]);
    }
  }
}

// ---------------- gather conv: one wave per node, lane = feature dim ----------------
template<bool RELU>
__global__ __launch_bounds__(256) void k_gather(
    const int* __restrict__ off, const unsigned* __restrict__ pairs,
    const float* __restrict__ dinv,
    const u16* __restrict__ xw, const float* __restrict__ bias,
    u16* __restrict__ h, int n) {
  int gid = blockIdx.x * 256 + threadIdx.x;
  int c = gid >> 6, lane = gid & 63;
  if (c >= n) return;
  float s = dinv[c]; s *= s;
  float acc = fmaf(bf2f(xw[(size_t)c * 64 + lane]), s, bias[lane]);
  int i = off[c], end = off[c + 1];
  for (; i + 7 < end; i += 8) {
    unsigned p[8];
    float v[8];
    #pragma unroll
    for (int t = 0; t < 8; ++t) p[t] = pairs[i + t];
    #pragma unroll
    for (int t = 0; t < 8; ++t)
      v[t] = bf2f(xw[(size_t)(p[t] >> 16) * 64 + lane]);
    #pragma unroll
    for (int t = 0; t < 8; ++t)
      acc = fmaf(v[t], __uint_as_float((p[t] & 0xffffu) << 16), acc);
  }
  for (; i + 1 < end; i += 2) {
    unsigned p0 = pairs[i], p1 = pairs[i + 1];
    float v0 = bf2f(xw[(size_t)(p0 >> 16) * 64 + lane]);
    float v1 = bf2f(xw[(size_t)(p1 >> 16) * 64 + lane]);
    acc = fmaf(v0, __uint_as_float((p0 & 0xffffu) << 16), acc);
    acc = fmaf(v1, __uint_as_float((p1 & 0xffffu) << 16), acc);
  }
  if (i < end) {
    unsigned p = pairs[i];
    acc = fmaf(bf2f(xw[(size_t)(p >> 16) * 64 + lane]),
               __uint_as_float((p & 0xffffu) << 16), acc);
  }
  if (RELU) acc = fmaxf(acc, 0.f);
  h[(size_t)c * 64 + lane] = f2bfu(acc);
}

// ---------------- fused FC head (h in bf16) ----------------
__global__ __launch_bounds__(256) void k_fc(
    const u16* __restrict__ h,
    const float* __restrict__ fW1, const float* __restrict__ fb1,
    const float* __restrict__ fW2, const float* __restrict__ fb2,
    float* __restrict__ out, int M) {
  __shared__ float Hs[64][68];
  __shared__ float Ws[64][48];
  __shared__ float bs[48];
  const int t = threadIdx.x;
  const int row0 = blockIdx.x * 64;
  #pragma unroll
  for (int i = 0; i < 4; ++i) {
    int f = t + i * 256;
    int r = f >> 4, k4 = f & 15;
    int rr = row0 + r;
    float4 v = make_float4(0.f, 0.f, 0.f, 0.f);
    if (rr < M) {
      u16x4 u = *(const u16x4*)&h[(size_t)rr * 64 + k4 * 4];
      v = make_float4(bf2f(u[0]), bf2f(u[1]), bf2f(u[2]), bf2f(u[3]));
    }
    *(float4*)&Hs[r][k4 * 4] = v;
  }
  for (int f = t; f < 64 * 48; f += 256) {
    int k = f / 48, c = f - k * 48;
    Ws[k][c] = (c < 16) ? fW1[k * 16 + c] : fW2[k * 32 + (c - 16)];
  }
  if (t < 48) bs[t] = (t < 16) ? fb1[t] : fb2[t - 16];
  __syncthreads();
  const int tr = t >> 4, tc = t & 15;
  float acc[4][3] = {{0.f}};
  #pragma unroll 8
  for (int k = 0; k < 64; ++k) {
    float a[4], b[3];
    #pragma unroll
    for (int i = 0; i < 4; ++i) a[i] = Hs[tr * 4 + i][k];
    #pragma unroll
    for (int j = 0; j < 3; ++j) b[j] = Ws[k][tc * 3 + j];
    #pragma unroll
    for (int i = 0; i < 4; ++i)
      #pragma unroll
      for (int j = 0; j < 3; ++j) acc[i][j] = fmaf(a[i], b[j], acc[i][j]);
  }
  #pragma unroll
  for (int i = 0; i < 4; ++i) {
    int rr = row0 + tr * 4 + i;
    if (rr >= M) continue;
    #pragma unroll
    for (int j = 0; j < 3; ++j) {
      int c = tc * 3 + j;
      float v = acc[i][j] + bs[c];
      if (c < 16) out[(size_t)rr * 16 + c] = v;
      else out[(size_t)M * 16 + (size_t)rr * 32 + (c - 16)] = v;
    }
  }
}

extern "C" void kernel_launch(void* const* d_in, const int* in_sizes, int n_in,
                              void* d_out, int out_size, void* d_ws, size_t ws_size,
                              hipStream_t stream) {
  const float* x    = (const float*)d_in[0];
  const int*   ei   = (const int*)d_in[1];
  const float* ew   = (const float*)d_in[2];
  const float* W1   = (const float*)d_in[3];
  const float* b1   = (const float*)d_in[4];
  const float* W2   = (const float*)d_in[5];
  const float* b2   = (const float*)d_in[6];
  const float* fW1  = (const float*)d_in[7];
  const float* fb1  = (const float*)d_in[8];
  const float* fW2  = (const float*)d_in[9];
  const float* fb2  = (const float*)d_in[10];
  float* out = (float*)d_out;

  const int N = in_sizes[0] / N_FEAT;      // 50000 < 65536 (16-bit src pack)
  const int E = in_sizes[2];
  const int H = (N + 63) & ~63;
  const int* row = ei;
  const int* col = ei + E;

  char* ws = (char*)d_ws;
  float*              dinv = (float*)(ws + 0x000000);               // N f
  int*                off  = (int*)  (ws + 0x080000);               // N+1 i
  int*                bsum = (int*)  (ws + 0x0C0000);
  int*                bsum2= (int*)  (ws + 0x0C1000);
  short*              BF1  = (short*)(ws + 0x0C8000);               // 64KB frag-order B1
  short*              BF2  = (short*)(ws + 0x0DA000);               // 9KB frag-order B2
  unsigned long long* hist = (unsigned long long*)(ws + 0x100000);  // 8*H u64 (3.2MB)
  int*                cur  = (int*)  (ws + 0x500000);               // FILL_REPS*8*H i (4.8MB)
  unsigned*           pairs= (unsigned*)(ws + 0xB00000);            // FILL_REPS*E u32 (9.6MB)
  u16*                bufA = (u16*)  (ws + 0x1500000);              // N*64 bf16 (6.4MB)
  u16*                bufB = (u16*)  (ws + 0x1C00000);              // N*64 bf16 (6.4MB)

  const int nbN  = (N + 255) / 256;
  const int nbE  = (E + 255) / 256;
  const int nbS  = (N + 63) / 64;          // 64-row staged-GEMM blocks
  const int nbT  = (N + 15) / 16;          // 16-row register-GEMM blocks
  const int nbG  = (N + 63) / 64;
  const int nbW  = (N * 64 + 255) / 256;
  const int nH16 = NPART * H / 2;          // hist size in uint4 units
  const int nbZ  = (nH16 + 255) / 256;

  // ---- weight pre-pack into MFMA fragment order (bf16) ----
  k_prepBF<<<32, 256, 0, stream>>>(W1, BF1, N_FEAT);
  k_prepBF<<<2,  256, 0, stream>>>(W2, BF2, N_HID);

  // ---- CSR build (shared by both conv layers) ----
  k_zeroH  <<<nbZ, 256, 0, stream>>>((uint4*)hist, nH16);
  k_degcnt2<<<nbE, 256, 0, stream>>>(col, ew, hist, H, E);
  k_redscan<<<nbN, 256, 0, stream>>>(hist, H, dinv, off, bsum, N);
  k_scan2  <<<1,   256, 0, stream>>>(bsum, bsum2, nbN);
  k_scan3_initcur<<<nbN, 256, 0, stream>>>(off, bsum2, hist, H, cur, N, E);
  k_fill2p <<<nbE, 256, 0, stream>>>(row, col, ew, dinv, cur, H, pairs, E);

  // ---- layer 1: xw1 = x@W1 (PROBE: x4 reps); h1 = relu(conv) ----
  k_mfma512p<<<nbS, 256, 0, stream>>>(x, (const short8*)BF1, bufA, N);
  k_gather<true><<<nbW, 256, 0, stream>>>(off, pairs, dinv, bufA, b1, bufB, N);

  // ---- layer 2: xw2 = h1@W2 (register MFMA, bf16 A); h2 = conv ----
  k_mfma64<<<nbT, 64, 0, stream>>>(bufB, (const short8*)BF2, bufA, N);
  k_gather<false><<<nbW, 256, 0, stream>>>(off, pairs, dinv, bufA, b2, bufB, N);

  // ---- FC heads ----
  k_fc<<<nbG, 256, 0, stream>>>(bufB, fW1, fb1, fW2, fb2, out, N);
}

// Round 12
// 203.687 us; speedup vs baseline: 2.7893x; 2.7893x over previous
//
#include <hip/hip_runtime.h>
#include <hip/hip_bf16.h>
#include <cstdint>
#include <cstddef>

#define N_FEAT 512
#define N_HID 64
#define N_CLASS 16
#define N_CLUSTER 32
#define NPART 8          // privatized histogram partitions
#define KSPLIT 4         // K-split factor for layer-1 GEMM (TLP x4)

typedef short short8 __attribute__((ext_vector_type(8)));
typedef float floatx4 __attribute__((ext_vector_type(4)));
typedef unsigned short u16;
typedef unsigned short u16x4 __attribute__((ext_vector_type(4)));
typedef unsigned short u16x8 __attribute__((ext_vector_type(8)));

__device__ __forceinline__ short f2bf(float f) {
  __hip_bfloat16 h = __float2bfloat16(f);   // RNE
  return *reinterpret_cast<short*>(&h);
}
__device__ __forceinline__ u16 f2bfu(float f) { return (u16)f2bf(f); }
__device__ __forceinline__ float bf2f(u16 u) {
  return __uint_as_float((unsigned)u << 16);
}

// ---------------- fast zero-fill ----------------
__global__ void k_zeroH(uint4* __restrict__ p, int n16) {
  int i = blockIdx.x * 256 + threadIdx.x;
  if (i < n16) p[i] = make_uint4(0u, 0u, 0u, 0u);
}

// ---------------- packed degree/count histogram: one u64 atomic per edge ----------------
__global__ void k_degcnt2(const int* __restrict__ col, const float* __restrict__ w,
                          unsigned long long* __restrict__ hist, int H, int E) {
  int e = blockIdx.x * 256 + threadIdx.x;
  if (e >= E) return;
  int p = blockIdx.x & (NPART - 1);
  int c = col[e];
  unsigned long long fx = (unsigned long long)__float2uint_rn(w[e] * 16777216.0f);
  atomicAdd(&hist[(size_t)p * H + c], (1ull << 40) | fx);
}

// ---------------- fold partitions + exclusive scan (merged) ----------------
__global__ __launch_bounds__(256) void k_redscan(
    const unsigned long long* __restrict__ hist, int H,
    float* __restrict__ dinv, int* __restrict__ off,
    int* __restrict__ bsum, int n) {
  __shared__ int sh[256];
  int t = threadIdx.x;
  int i = blockIdx.x * 256 + t;
  int v = 0;
  if (i < n) {
    unsigned long long tot = 0;
    #pragma unroll
    for (int p = 0; p < NPART; ++p) tot += hist[(size_t)p * H + i];
    v = (int)(tot >> 40);
    float wsum = (float)(tot & ((1ull << 40) - 1)) * 5.9604644775390625e-08f; // 2^-24
    dinv[i] = rsqrtf(1.0f + wsum);
  }
  sh[t] = v;
  __syncthreads();
  #pragma unroll
  for (int d = 1; d < 256; d <<= 1) {
    int x = 0;
    if (t >= d) x = sh[t - d];
    __syncthreads();
    if (t >= d) sh[t] += x;
    __syncthreads();
  }
  if (i < n) off[i] = sh[t] - v;
  if (t == 255) bsum[blockIdx.x] = sh[255];
}

__global__ __launch_bounds__(256) void k_scan2(const int* __restrict__ bsum,
                                               int* __restrict__ bsum2, int nb) {
  __shared__ int sh[256];
  int t = threadIdx.x;
  int v = (t < nb) ? bsum[t] : 0;
  sh[t] = v;
  __syncthreads();
  #pragma unroll
  for (int d = 1; d < 256; d <<= 1) {
    int x = 0;
    if (t >= d) x = sh[t - d];
    __syncthreads();
    if (t >= d) sh[t] += x;
    __syncthreads();
  }
  if (t < nb) bsum2[t] = sh[t] - v;
}

__global__ void k_scan3_initcur(int* __restrict__ off, const int* __restrict__ bsum2,
                                const unsigned long long* __restrict__ hist, int H,
                                int* __restrict__ cur, int n, int E) {
  int i = blockIdx.x * 256 + threadIdx.x;
  if (i < n) {
    int o = off[i] + bsum2[blockIdx.x];
    off[i] = o;
    int running = o;
    #pragma unroll
    for (int p = 0; p < NPART; ++p) {
      cur[(size_t)p * H + i] = running;
      running += (int)(hist[(size_t)p * H + i] >> 40);
    }
  }
  if (i == 0) off[n] = E;
}

// ---------------- fill CSR slots: ONE 4B (src16 | coef-bf16) store per edge ----------------
__global__ void k_fill2(const int* __restrict__ rowi, const int* __restrict__ coli,
                        const float* __restrict__ w, const float* __restrict__ dinv,
                        int* __restrict__ cur, int H,
                        unsigned* __restrict__ pairs, int E) {
  int e = blockIdx.x * 256 + threadIdx.x;
  if (e >= E) return;
  int p = blockIdx.x & (NPART - 1);       // must match k_degcnt2's mapping
  int r = rowi[e], c = coli[e];
  int pos = atomicAdd(&cur[(size_t)p * H + c], 1);
  pairs[pos] = ((unsigned)r << 16) | (u16)f2bf(dinv[r] * w[e] * dinv[c]);
}

// ---------------- W[K][64] fp32 -> BF in MFMA-fragment order (bf16) ----------------
__global__ void k_prepBF(const float* __restrict__ W, short* __restrict__ BF, int K) {
  int idx = blockIdx.x * 256 + threadIdx.x;
  int total = (K / 32) * 4 * 64;
  if (idx >= total) return;
  int lane = idx & 63;
  int sj = idx >> 6;
  int j = sj & 3, s = sj >> 2;
  int col = j * 16 + (lane & 15);
  int k0 = s * 32 + ((lane >> 4) << 3);
  short8 v;
  #pragma unroll
  for (int t = 0; t < 8; ++t) v[t] = f2bf(W[(size_t)(k0 + t) * 64 + col]);
  *(short8*)(BF + (size_t)idx * 8) = v;
}

// ---------------- layer-1 GEMM, K-split x4: Cp[q] = x[:,q*128:+128] @ W1[q*128:+128,:] ----
// One wave per (q, 16-row tile): grid = 4*nbT single-wave blocks -> ~20 waves/CU
// (round-11 probe: 27% occupancy, all pipes idle => TLP-starved). All 8 A-loads
// issued up-front (no chunk drains); B double-buffered from L2-hot BF table.
__global__ __launch_bounds__(64, 5) void k_mfma128(
    const float* __restrict__ A, const short8* __restrict__ BF,
    u16* __restrict__ Cp, int M, int nbT) {
  const int q = blockIdx.x / nbT;          // K-quarter
  const int tb = blockIdx.x - q * nbT;     // row tile
  const int lane = threadIdx.x & 63;
  const int rbase = tb * 16;
  int r = rbase + (lane & 15);
  if (r >= M) r = M - 1;                   // only its own D-row is garbage
  const float* arow = A + (size_t)r * 512 + q * 128 + ((lane >> 4) << 3);
  const short8* bbase = BF + q * 1024 + lane;   // 4 steps * 4 j * 64 lanes per quarter

  // ---- all A loads up-front: 4 steps x 2 float4 = 8 HBM loads in flight ----
  float4 a[8];
  #pragma unroll
  for (int s = 0; s < 4; ++s) {
    a[2 * s]     = *(const float4*)(arow + s * 32);
    a[2 * s + 1] = *(const float4*)(arow + s * 32 + 4);
  }
  // ---- B: double-buffered 2-step (L2-hot) ----
  short8 pb[2][4];
  #pragma unroll
  for (int s = 0; s < 2; ++s)
    #pragma unroll
    for (int j = 0; j < 4; ++j)
      pb[s][j] = bbase[(s * 4 + j) * 64];
  __builtin_amdgcn_sched_barrier(0);       // keep prologue loads issued up-front

  floatx4 acc[4];
  #pragma unroll
  for (int j = 0; j < 4; ++j) acc[j] = (floatx4){0.f, 0.f, 0.f, 0.f};

  #pragma unroll
  for (int s = 0; s < 4; ++s) {
    const int sb = s & 1;
    float4 a0 = a[2 * s], a1 = a[2 * s + 1];
    short8 af;
    af[0] = f2bf(a0.x); af[1] = f2bf(a0.y); af[2] = f2bf(a0.z); af[3] = f2bf(a0.w);
    af[4] = f2bf(a1.x); af[5] = f2bf(a1.y); af[6] = f2bf(a1.z); af[7] = f2bf(a1.w);
    acc[0] = __builtin_amdgcn_mfma_f32_16x16x32_bf16(af, pb[sb][0], acc[0], 0, 0, 0);
    acc[1] = __builtin_amdgcn_mfma_f32_16x16x32_bf16(af, pb[sb][1], acc[1], 0, 0, 0);
    acc[2] = __builtin_amdgcn_mfma_f32_16x16x32_bf16(af, pb[sb][2], acc[2], 0, 0, 0);
    acc[3] = __builtin_amdgcn_mfma_f32_16x16x32_bf16(af, pb[sb][3], acc[3], 0, 0, 0);
    if (s + 2 < 4) {
      #pragma unroll
      for (int j = 0; j < 4; ++j)
        pb[sb][j] = bbase[((s + 2) * 4 + j) * 64];
    }
    __builtin_amdgcn_sched_barrier(0);
  }

  u16* Cq = Cp + (size_t)q * M * 64;
  const int srow = rbase + (lane >> 4) * 4;
  const int scol = lane & 15;
  #pragma unroll
  for (int i = 0; i < 4; ++i) {
    int rr = srow + i;
    if (rr < M) {
      #pragma unroll
      for (int j = 0; j < 4; ++j)
        Cq[(size_t)rr * 64 + j * 16 + scol] = f2bfu(acc[j][i]);
    }
  }
}

// ---------------- combine K-split partials: Cf = sum_q Cp[q] (bf16) ----------------
__global__ void k_comb(const u16* __restrict__ Cp, u16* __restrict__ Cf,
                       int n8, int part) {
  int i = blockIdx.x * 256 + threadIdx.x;
  if (i >= n8) return;
  u16x8 p0 = *(const u16x8*)(Cp + (size_t)i * 8);
  u16x8 p1 = *(const u16x8*)(Cp + (size_t)part + i * 8);
  u16x8 p2 = *(const u16x8*)(Cp + (size_t)2 * part + i * 8);
  u16x8 p3 = *(const u16x8*)(Cp + (size_t)3 * part + i * 8);
  u16x8 o;
  #pragma unroll
  for (int j = 0; j < 8; ++j)
    o[j] = f2bfu((bf2f(p0[j]) + bf2f(p1[j])) + (bf2f(p2[j]) + bf2f(p3[j])));
  *(u16x8*)(Cf + (size_t)i * 8) = o;
}

// ---------------- layer-2 MFMA GEMM (K=64, bf16 A, L2-hot): register version ----------------
__global__ __launch_bounds__(64, 4) void k_mfma64(
    const u16* __restrict__ Av, const short8* __restrict__ BF,
    u16* __restrict__ C, int M) {
  const int lane = threadIdx.x & 63;
  const int rbase = blockIdx.x * 16;
  int r = rbase + (lane & 15);
  if (r >= M) r = M - 1;
  const int klo = (lane >> 4) * 8;
  const u16* arow = Av + (size_t)r * 64 + klo;
  const short8* bbase = BF + lane;

  short8 pah[2];
  short8 pb[2][4];
  pah[0] = *(const short8*)(arow);
  pah[1] = *(const short8*)(arow + 32);
  #pragma unroll
  for (int s = 0; s < 2; ++s)
    #pragma unroll
    for (int j = 0; j < 4; ++j)
      pb[s][j] = bbase[(s * 4 + j) * 64];

  floatx4 acc[4];
  #pragma unroll
  for (int j = 0; j < 4; ++j) acc[j] = (floatx4){0.f, 0.f, 0.f, 0.f};

  #pragma unroll
  for (int s = 0; s < 2; ++s) {
    acc[0] = __builtin_amdgcn_mfma_f32_16x16x32_bf16(pah[s], pb[s][0], acc[0], 0, 0, 0);
    acc[1] = __builtin_amdgcn_mfma_f32_16x16x32_bf16(pah[s], pb[s][1], acc[1], 0, 0, 0);
    acc[2] = __builtin_amdgcn_mfma_f32_16x16x32_bf16(pah[s], pb[s][2], acc[2], 0, 0, 0);
    acc[3] = __builtin_amdgcn_mfma_f32_16x16x32_bf16(pah[s], pb[s][3], acc[3], 0, 0, 0);
  }

  const int srow = rbase + (lane >> 4) * 4;
  const int scol = lane & 15;
  #pragma unroll
  for (int i = 0; i < 4; ++i) {
    int rr = srow + i;
    if (rr < M) {
      #pragma unroll
      for (int j = 0; j < 4; ++j)
        C[(size_t)rr * 64 + j * 16 + scol] = f2bfu(acc[j][i]);
    }
  }
}

// ---------------- gather conv: one wave per node, lane = feature dim ----------------
template<bool RELU>
__global__ __launch_bounds__(256) void k_gather(
    const int* __restrict__ off, const unsigned* __restrict__ pairs,
    const float* __restrict__ dinv,
    const u16* __restrict__ xw, const float* __restrict__ bias,
    u16* __restrict__ h, int n) {
  int gid = blockIdx.x * 256 + threadIdx.x;
  int c = gid >> 6, lane = gid & 63;
  if (c >= n) return;
  float s = dinv[c]; s *= s;
  float acc = fmaf(bf2f(xw[(size_t)c * 64 + lane]), s, bias[lane]);
  int i = off[c], end = off[c + 1];
  for (; i + 7 < end; i += 8) {
    unsigned p[8];
    float v[8];
    #pragma unroll
    for (int t = 0; t < 8; ++t) p[t] = pairs[i + t];
    #pragma unroll
    for (int t = 0; t < 8; ++t)
      v[t] = bf2f(xw[(size_t)(p[t] >> 16) * 64 + lane]);
    #pragma unroll
    for (int t = 0; t < 8; ++t)
      acc = fmaf(v[t], __uint_as_float((p[t] & 0xffffu) << 16), acc);
  }
  for (; i + 1 < end; i += 2) {
    unsigned p0 = pairs[i], p1 = pairs[i + 1];
    float v0 = bf2f(xw[(size_t)(p0 >> 16) * 64 + lane]);
    float v1 = bf2f(xw[(size_t)(p1 >> 16) * 64 + lane]);
    acc = fmaf(v0, __uint_as_float((p0 & 0xffffu) << 16), acc);
    acc = fmaf(v1, __uint_as_float((p1 & 0xffffu) << 16), acc);
  }
  if (i < end) {
    unsigned p = pairs[i];
    acc = fmaf(bf2f(xw[(size_t)(p >> 16) * 64 + lane]),
               __uint_as_float((p & 0xffffu) << 16), acc);
  }
  if (RELU) acc = fmaxf(acc, 0.f);
  h[(size_t)c * 64 + lane] = f2bfu(acc);
}

// ---------------- fused FC head (h in bf16) ----------------
__global__ __launch_bounds__(256) void k_fc(
    const u16* __restrict__ h,
    const float* __restrict__ fW1, const float* __restrict__ fb1,
    const float* __restrict__ fW2, const float* __restrict__ fb2,
    float* __restrict__ out, int M) {
  __shared__ float Hs[64][68];
  __shared__ float Ws[64][48];
  __shared__ float bs[48];
  const int t = threadIdx.x;
  const int row0 = blockIdx.x * 64;
  #pragma unroll
  for (int i = 0; i < 4; ++i) {
    int f = t + i * 256;
    int r = f >> 4, k4 = f & 15;
    int rr = row0 + r;
    float4 v = make_float4(0.f, 0.f, 0.f, 0.f);
    if (rr < M) {
      u16x4 u = *(const u16x4*)&h[(size_t)rr * 64 + k4 * 4];
      v = make_float4(bf2f(u[0]), bf2f(u[1]), bf2f(u[2]), bf2f(u[3]));
    }
    *(float4*)&Hs[r][k4 * 4] = v;
  }
  for (int f = t; f < 64 * 48; f += 256) {
    int k = f / 48, c = f - k * 48;
    Ws[k][c] = (c < 16) ? fW1[k * 16 + c] : fW2[k * 32 + (c - 16)];
  }
  if (t < 48) bs[t] = (t < 16) ? fb1[t] : fb2[t - 16];
  __syncthreads();
  const int tr = t >> 4, tc = t & 15;
  float acc[4][3] = {{0.f}};
  #pragma unroll 8
  for (int k = 0; k < 64; ++k) {
    float a[4], b[3];
    #pragma unroll
    for (int i = 0; i < 4; ++i) a[i] = Hs[tr * 4 + i][k];
    #pragma unroll
    for (int j = 0; j < 3; ++j) b[j] = Ws[k][tc * 3 + j];
    #pragma unroll
    for (int i = 0; i < 4; ++i)
      #pragma unroll
      for (int j = 0; j < 3; ++j) acc[i][j] = fmaf(a[i], b[j], acc[i][j]);
  }
  #pragma unroll
  for (int i = 0; i < 4; ++i) {
    int rr = row0 + tr * 4 + i;
    if (rr >= M) continue;
    #pragma unroll
    for (int j = 0; j < 3; ++j) {
      int c = tc * 3 + j;
      float v = acc[i][j] + bs[c];
      if (c < 16) out[(size_t)rr * 16 + c] = v;
      else out[(size_t)M * 16 + (size_t)rr * 32 + (c - 16)] = v;
    }
  }
}

extern "C" void kernel_launch(void* const* d_in, const int* in_sizes, int n_in,
                              void* d_out, int out_size, void* d_ws, size_t ws_size,
                              hipStream_t stream) {
  const float* x    = (const float*)d_in[0];
  const int*   ei   = (const int*)d_in[1];
  const float* ew   = (const float*)d_in[2];
  const float* W1   = (const float*)d_in[3];
  const float* b1   = (const float*)d_in[4];
  const float* W2   = (const float*)d_in[5];
  const float* b2   = (const float*)d_in[6];
  const float* fW1  = (const float*)d_in[7];
  const float* fb1  = (const float*)d_in[8];
  const float* fW2  = (const float*)d_in[9];
  const float* fb2  = (const float*)d_in[10];
  float* out = (float*)d_out;

  const int N = in_sizes[0] / N_FEAT;      // 50000 < 65536 (16-bit src pack)
  const int E = in_sizes[2];
  const int H = (N + 63) & ~63;
  const int* row = ei;
  const int* col = ei + E;

  char* ws = (char*)d_ws;
  float*              dinv = (float*)(ws + 0x000000);               // N f
  int*                off  = (int*)  (ws + 0x080000);               // N+1 i
  int*                bsum = (int*)  (ws + 0x0C0000);
  int*                bsum2= (int*)  (ws + 0x0C1000);
  short*              BF1  = (short*)(ws + 0x0C8000);               // 64KB frag-order B1
  short*              BF2  = (short*)(ws + 0x0DA000);               // 8KB frag-order B2
  unsigned long long* hist = (unsigned long long*)(ws + 0x100000);  // 8*H u64 (3.2MB)
  int*                cur  = (int*)  (ws + 0x500000);               // 8*H i (1.6MB)
  unsigned*           pairs= (unsigned*)(ws + 0x6C0000);            // E u32 (3.2MB)
  u16*                Cp   = (u16*)  (ws + 0xA00000);               // 4 x N*64 bf16 (25.6MB)
  u16*                bufA = (u16*)  (ws + 0x2400000);              // N*64 bf16 (6.4MB)
  u16*                bufB = (u16*)  (ws + 0x2B00000);              // N*64 bf16 (6.4MB)

  const int nbN  = (N + 255) / 256;
  const int nbE  = (E + 255) / 256;
  const int nbT  = (N + 15) / 16;          // 16-row tiles
  const int nbG  = (N + 63) / 64;
  const int nbW  = (N * 64 + 255) / 256;
  const int nH16 = NPART * H / 2;          // hist size in uint4 units
  const int nbZ  = (nH16 + 255) / 256;
  const int n8   = N * 64 / 8;
  const int nbC  = (n8 + 255) / 256;

  // ---- weight pre-pack into MFMA fragment order (bf16) ----
  k_prepBF<<<32, 256, 0, stream>>>(W1, BF1, N_FEAT);
  k_prepBF<<<2,  256, 0, stream>>>(W2, BF2, N_HID);

  // ---- CSR build (shared by both conv layers) ----
  k_zeroH  <<<nbZ, 256, 0, stream>>>((uint4*)hist, nH16);
  k_degcnt2<<<nbE, 256, 0, stream>>>(col, ew, hist, H, E);
  k_redscan<<<nbN, 256, 0, stream>>>(hist, H, dinv, off, bsum, N);
  k_scan2  <<<1,   256, 0, stream>>>(bsum, bsum2, nbN);
  k_scan3_initcur<<<nbN, 256, 0, stream>>>(off, bsum2, hist, H, cur, N, E);
  k_fill2  <<<nbE, 256, 0, stream>>>(row, col, ew, dinv, cur, H, pairs, E);

  // ---- layer 1: xw1 = x@W1 via K-split x4 + combine; h1 = relu(conv) ----
  k_mfma128<<<KSPLIT * nbT, 64, 0, stream>>>(x, (const short8*)BF1, Cp, N, nbT);
  k_comb   <<<nbC, 256, 0, stream>>>(Cp, bufA, n8, N * 64);
  k_gather<true><<<nbW, 256, 0, stream>>>(off, pairs, dinv, bufA, b1, bufB, N);

  // ---- layer 2: xw2 = h1@W2 (register MFMA, bf16 A); h2 = conv ----
  k_mfma64<<<nbT, 64, 0, stream>>>(bufB, (const short8*)BF2, bufA, N);
  k_gather<false><<<nbW, 256, 0, stream>>>(off, pairs, dinv, bufA, b2, bufB, N);

  // ---- FC heads ----
  k_fc<<<nbG, 256, 0, stream>>>(bufB, fW1, fb1, fW2, fb2, out, N);
}

// Round 13
// 188.796 us; speedup vs baseline: 3.0093x; 1.0789x over previous
//
#include <hip/hip_runtime.h>
#include <hip/hip_bf16.h>
#include <cstdint>
#include <cstddef>

#define N_FEAT 512
#define N_HID 64
#define N_CLASS 16
#define N_CLUSTER 32
#define NPART 8          // privatized histogram partitions

typedef short short8 __attribute__((ext_vector_type(8)));
typedef float floatx4 __attribute__((ext_vector_type(4)));
typedef unsigned short u16;
typedef unsigned short u16x4 __attribute__((ext_vector_type(4)));

__device__ __forceinline__ short f2bf(float f) {
  __hip_bfloat16 h = __float2bfloat16(f);   // RNE
  return *reinterpret_cast<short*>(&h);
}
__device__ __forceinline__ u16 f2bfu(float f) { return (u16)f2bf(f); }
__device__ __forceinline__ float bf2f(u16 u) {
  return __uint_as_float((unsigned)u << 16);
}

// ---------------- W[K][64] fp32 -> BF in MFMA-fragment order (bf16), granule body ----
__device__ __forceinline__ void prepBF_one(const float* __restrict__ W,
                                           short* __restrict__ BF, int K, int idx) {
  int lane = idx & 63;
  int sj = idx >> 6;
  int j = sj & 3, s = sj >> 2;
  int col = j * 16 + (lane & 15);
  int k0 = s * 32 + ((lane >> 4) << 3);
  short8 v;
  #pragma unroll
  for (int t = 0; t < 8; ++t) v[t] = f2bf(W[(size_t)(k0 + t) * 64 + col]);
  *(short8*)(BF + (size_t)idx * 8) = v;
}

// ---------------- merged init: zero hist + pre-pack both weight tables ----------------
__global__ void k_init(uint4* __restrict__ h16, int n16,
                       const float* __restrict__ W1, short* __restrict__ BF1,
                       const float* __restrict__ W2, short* __restrict__ BF2,
                       int nbZ) {
  int b = blockIdx.x, t = threadIdx.x;
  if (b < nbZ) {
    int i = b * 256 + t;
    if (i < n16) h16[i] = make_uint4(0u, 0u, 0u, 0u);
  } else if (b < nbZ + 16) {
    prepBF_one(W1, BF1, N_FEAT, (b - nbZ) * 256 + t);      // 4096 granules
  } else {
    int idx = (b - nbZ - 16) * 256 + t;
    if (idx < 512) prepBF_one(W2, BF2, N_HID, idx);        // 512 granules
  }
}

// ---------------- packed degree/count histogram: one u64 atomic per edge ----------------
__global__ void k_degcnt2(const int* __restrict__ col, const float* __restrict__ w,
                          unsigned long long* __restrict__ hist, int H, int E) {
  int e = blockIdx.x * 256 + threadIdx.x;
  if (e >= E) return;
  int p = blockIdx.x & (NPART - 1);
  int c = col[e];
  unsigned long long fx = (unsigned long long)__float2uint_rn(w[e] * 16777216.0f);
  atomicAdd(&hist[(size_t)p * H + c], (1ull << 40) | fx);
}

// ---------------- fold partitions + exclusive scan (merged) ----------------
__global__ __launch_bounds__(256) void k_redscan(
    const unsigned long long* __restrict__ hist, int H,
    float* __restrict__ dinv, int* __restrict__ off,
    int* __restrict__ bsum, int n) {
  __shared__ int sh[256];
  int t = threadIdx.x;
  int i = blockIdx.x * 256 + t;
  int v = 0;
  if (i < n) {
    unsigned long long tot = 0;
    #pragma unroll
    for (int p = 0; p < NPART; ++p) tot += hist[(size_t)p * H + i];
    v = (int)(tot >> 40);
    float wsum = (float)(tot & ((1ull << 40) - 1)) * 5.9604644775390625e-08f; // 2^-24
    dinv[i] = rsqrtf(1.0f + wsum);
  }
  sh[t] = v;
  __syncthreads();
  #pragma unroll
  for (int d = 1; d < 256; d <<= 1) {
    int x = 0;
    if (t >= d) x = sh[t - d];
    __syncthreads();
    if (t >= d) sh[t] += x;
    __syncthreads();
  }
  if (i < n) off[i] = sh[t] - v;
  if (t == 255) bsum[blockIdx.x] = sh[255];
}

__global__ __launch_bounds__(256) void k_scan2(const int* __restrict__ bsum,
                                               int* __restrict__ bsum2, int nb) {
  __shared__ int sh[256];
  int t = threadIdx.x;
  int v = (t < nb) ? bsum[t] : 0;
  sh[t] = v;
  __syncthreads();
  #pragma unroll
  for (int d = 1; d < 256; d <<= 1) {
    int x = 0;
    if (t >= d) x = sh[t - d];
    __syncthreads();
    if (t >= d) sh[t] += x;
    __syncthreads();
  }
  if (t < nb) bsum2[t] = sh[t] - v;
}

__global__ void k_scan3_initcur(int* __restrict__ off, const int* __restrict__ bsum2,
                                const unsigned long long* __restrict__ hist, int H,
                                int* __restrict__ cur, int n, int E) {
  int i = blockIdx.x * 256 + threadIdx.x;
  if (i < n) {
    int o = off[i] + bsum2[blockIdx.x];
    off[i] = o;
    int running = o;
    #pragma unroll
    for (int p = 0; p < NPART; ++p) {
      cur[(size_t)p * H + i] = running;
      running += (int)(hist[(size_t)p * H + i] >> 40);
    }
  }
  if (i == 0) off[n] = E;
}

// ---------------- GEMM wave body: one 16-row x 64-col tile over K=512 ----------------
// Round-9 register structure: PA=4 A-slots, PB=2 B-slots, sched_barrier pins.
__device__ __forceinline__ void gemm_wave(
    const float* __restrict__ A, const short8* __restrict__ BF,
    u16* __restrict__ C, int M, int tile) {
  const int lane = threadIdx.x & 63;
  const int rbase = tile * 16;
  int r = rbase + (lane & 15);
  if (r >= M) r = M - 1;                    // only its own D-row is garbage
  const float* arow = A + (size_t)r * 512 + ((lane >> 4) << 3);
  const short8* bbase = BF + lane;

  float4 pa0[4], pa1[4];
  short8 pb[2][4];
  #pragma unroll
  for (int s = 0; s < 4; ++s) {
    pa0[s] = *(const float4*)(arow + s * 32);
    pa1[s] = *(const float4*)(arow + s * 32 + 4);
  }
  #pragma unroll
  for (int s = 0; s < 2; ++s)
    #pragma unroll
    for (int j = 0; j < 4; ++j)
      pb[s][j] = bbase[(s * 4 + j) * 64];
  __builtin_amdgcn_sched_barrier(0);        // prologue loads stay up-front

  floatx4 acc[4];
  #pragma unroll
  for (int j = 0; j < 4; ++j) acc[j] = (floatx4){0.f, 0.f, 0.f, 0.f};

  #pragma unroll
  for (int s = 0; s < 16; ++s) {
    const int sa = s & 3;
    const int sb = s & 1;
    float4 a0 = pa0[sa], a1 = pa1[sa];
    short8 af;
    af[0] = f2bf(a0.x); af[1] = f2bf(a0.y); af[2] = f2bf(a0.z); af[3] = f2bf(a0.w);
    af[4] = f2bf(a1.x); af[5] = f2bf(a1.y); af[6] = f2bf(a1.z); af[7] = f2bf(a1.w);
    acc[0] = __builtin_amdgcn_mfma_f32_16x16x32_bf16(af, pb[sb][0], acc[0], 0, 0, 0);
    acc[1] = __builtin_amdgcn_mfma_f32_16x16x32_bf16(af, pb[sb][1], acc[1], 0, 0, 0);
    acc[2] = __builtin_amdgcn_mfma_f32_16x16x32_bf16(af, pb[sb][2], acc[2], 0, 0, 0);
    acc[3] = __builtin_amdgcn_mfma_f32_16x16x32_bf16(af, pb[sb][3], acc[3], 0, 0, 0);
    if (s + 4 < 16) {
      pa0[sa] = *(const float4*)(arow + (s + 4) * 32);
      pa1[sa] = *(const float4*)(arow + (s + 4) * 32 + 4);
    }
    if (s + 2 < 16) {
      #pragma unroll
      for (int j = 0; j < 4; ++j)
        pb[sb][j] = bbase[((s + 2) * 4 + j) * 64];
    }
    __builtin_amdgcn_sched_barrier(0);      // refills can't sink past next MFMAs
  }

  const int srow = rbase + (lane >> 4) * 4;
  const int scol = lane & 15;
  #pragma unroll
  for (int i = 0; i < 4; ++i) {
    int rr = srow + i;
    if (rr < M) {
      #pragma unroll
      for (int j = 0; j < 4; ++j)
        C[(size_t)rr * 64 + j * 16 + scol] = f2bfu(acc[j][i]);
    }
  }
}

// ---------------- fill block body: 256 edges, one 4B pair store each ----------------
__device__ __forceinline__ void fill_block(
    int f, const int* __restrict__ rowi, const int* __restrict__ coli,
    const float* __restrict__ w, const float* __restrict__ dinv,
    int* __restrict__ cur, int H, unsigned* __restrict__ pairs, int E) {
  int e = f * 256 + threadIdx.x;
  if (e >= E) return;
  int p = f & (NPART - 1);                 // must match k_degcnt2's mapping
  int r = rowi[e], c = coli[e];
  int pos = atomicAdd(&cur[(size_t)p * H + c], 1);
  pairs[pos] = ((unsigned)r << 16) | (u16)f2bf(dinv[r] * w[e] * dinv[c]);
}

// ---------------- FUSED: layer-1 GEMM || CSR fill (independent work, co-scheduled) ----
// Every 5th block = GEMM (4 waves, each a 16-row x K=512 tile); other 4/5 = fill.
// GEMM is memory-read-throughput-bound, fill is scattered-atomic-latency-bound:
// neither saturates the machine alone (R11 probe: all pipes <5%), so overlap.
__global__ __launch_bounds__(256, 4) void k_gemmfill(
    const float* __restrict__ A, const short8* __restrict__ BF,
    u16* __restrict__ C, int M, int nbT,
    const int* __restrict__ rowi, const int* __restrict__ coli,
    const float* __restrict__ w, const float* __restrict__ dinv,
    int* __restrict__ cur, int H, unsigned* __restrict__ pairs, int E) {
  const int q = blockIdx.x / 5;
  const int r = blockIdx.x % 5;
  if (r == 0) {
    int tile = q * 4 + (threadIdx.x >> 6);
    if (tile < nbT) gemm_wave(A, BF, C, M, tile);
  } else {
    fill_block(q * 4 + (r - 1), rowi, coli, w, dinv, cur, H, pairs, E);
  }
}

// ---------------- layer-2 MFMA GEMM (K=64, bf16 A, L2-hot): register version ----------------
__global__ __launch_bounds__(64, 4) void k_mfma64(
    const u16* __restrict__ Av, const short8* __restrict__ BF,
    u16* __restrict__ C, int M) {
  const int lane = threadIdx.x & 63;
  const int rbase = blockIdx.x * 16;
  int r = rbase + (lane & 15);
  if (r >= M) r = M - 1;
  const int klo = (lane >> 4) * 8;
  const u16* arow = Av + (size_t)r * 64 + klo;
  const short8* bbase = BF + lane;

  short8 pah[2];
  short8 pb[2][4];
  pah[0] = *(const short8*)(arow);
  pah[1] = *(const short8*)(arow + 32);
  #pragma unroll
  for (int s = 0; s < 2; ++s)
    #pragma unroll
    for (int j = 0; j < 4; ++j)
      pb[s][j] = bbase[(s * 4 + j) * 64];

  floatx4 acc[4];
  #pragma unroll
  for (int j = 0; j < 4; ++j) acc[j] = (floatx4){0.f, 0.f, 0.f, 0.f};

  #pragma unroll
  for (int s = 0; s < 2; ++s) {
    acc[0] = __builtin_amdgcn_mfma_f32_16x16x32_bf16(pah[s], pb[s][0], acc[0], 0, 0, 0);
    acc[1] = __builtin_amdgcn_mfma_f32_16x16x32_bf16(pah[s], pb[s][1], acc[1], 0, 0, 0);
    acc[2] = __builtin_amdgcn_mfma_f32_16x16x32_bf16(pah[s], pb[s][2], acc[2], 0, 0, 0);
    acc[3] = __builtin_amdgcn_mfma_f32_16x16x32_bf16(pah[s], pb[s][3], acc[3], 0, 0, 0);
  }

  const int srow = rbase + (lane >> 4) * 4;
  const int scol = lane & 15;
  #pragma unroll
  for (int i = 0; i < 4; ++i) {
    int rr = srow + i;
    if (rr < M) {
      #pragma unroll
      for (int j = 0; j < 4; ++j)
        C[(size_t)rr * 64 + j * 16 + scol] = f2bfu(acc[j][i]);
    }
  }
}

// ---------------- gather conv: one wave per node, lane = feature dim ----------------
template<bool RELU>
__global__ __launch_bounds__(256) void k_gather(
    const int* __restrict__ off, const unsigned* __restrict__ pairs,
    const float* __restrict__ dinv,
    const u16* __restrict__ xw, const float* __restrict__ bias,
    u16* __restrict__ h, int n) {
  int gid = blockIdx.x * 256 + threadIdx.x;
  int c = gid >> 6, lane = gid & 63;
  if (c >= n) return;
  float s = dinv[c]; s *= s;
  float acc = fmaf(bf2f(xw[(size_t)c * 64 + lane]), s, bias[lane]);
  int i = off[c], end = off[c + 1];
  for (; i + 7 < end; i += 8) {
    unsigned p[8];
    float v[8];
    #pragma unroll
    for (int t = 0; t < 8; ++t) p[t] = pairs[i + t];
    #pragma unroll
    for (int t = 0; t < 8; ++t)
      v[t] = bf2f(xw[(size_t)(p[t] >> 16) * 64 + lane]);
    #pragma unroll
    for (int t = 0; t < 8; ++t)
      acc = fmaf(v[t], __uint_as_float((p[t] & 0xffffu) << 16), acc);
  }
  for (; i + 1 < end; i += 2) {
    unsigned p0 = pairs[i], p1 = pairs[i + 1];
    float v0 = bf2f(xw[(size_t)(p0 >> 16) * 64 + lane]);
    float v1 = bf2f(xw[(size_t)(p1 >> 16) * 64 + lane]);
    acc = fmaf(v0, __uint_as_float((p0 & 0xffffu) << 16), acc);
    acc = fmaf(v1, __uint_as_float((p1 & 0xffffu) << 16), acc);
  }
  if (i < end) {
    unsigned p = pairs[i];
    acc = fmaf(bf2f(xw[(size_t)(p >> 16) * 64 + lane]),
               __uint_as_float((p & 0xffffu) << 16), acc);
  }
  if (RELU) acc = fmaxf(acc, 0.f);
  h[(size_t)c * 64 + lane] = f2bfu(acc);
}

// ---------------- fused FC head (h in bf16) ----------------
__global__ __launch_bounds__(256) void k_fc(
    const u16* __restrict__ h,
    const float* __restrict__ fW1, const float* __restrict__ fb1,
    const float* __restrict__ fW2, const float* __restrict__ fb2,
    float* __restrict__ out, int M) {
  __shared__ float Hs[64][68];
  __shared__ float Ws[64][48];
  __shared__ float bs[48];
  const int t = threadIdx.x;
  const int row0 = blockIdx.x * 64;
  #pragma unroll
  for (int i = 0; i < 4; ++i) {
    int f = t + i * 256;
    int r = f >> 4, k4 = f & 15;
    int rr = row0 + r;
    float4 v = make_float4(0.f, 0.f, 0.f, 0.f);
    if (rr < M) {
      u16x4 u = *(const u16x4*)&h[(size_t)rr * 64 + k4 * 4];
      v = make_float4(bf2f(u[0]), bf2f(u[1]), bf2f(u[2]), bf2f(u[3]));
    }
    *(float4*)&Hs[r][k4 * 4] = v;
  }
  for (int f = t; f < 64 * 48; f += 256) {
    int k = f / 48, c = f - k * 48;
    Ws[k][c] = (c < 16) ? fW1[k * 16 + c] : fW2[k * 32 + (c - 16)];
  }
  if (t < 48) bs[t] = (t < 16) ? fb1[t] : fb2[t - 16];
  __syncthreads();
  const int tr = t >> 4, tc = t & 15;
  float acc[4][3] = {{0.f}};
  #pragma unroll 8
  for (int k = 0; k < 64; ++k) {
    float a[4], b[3];
    #pragma unroll
    for (int i = 0; i < 4; ++i) a[i] = Hs[tr * 4 + i][k];
    #pragma unroll
    for (int j = 0; j < 3; ++j) b[j] = Ws[k][tc * 3 + j];
    #pragma unroll
    for (int i = 0; i < 4; ++i)
      #pragma unroll
      for (int j = 0; j < 3; ++j) acc[i][j] = fmaf(a[i], b[j], acc[i][j]);
  }
  #pragma unroll
  for (int i = 0; i < 4; ++i) {
    int rr = row0 + tr * 4 + i;
    if (rr >= M) continue;
    #pragma unroll
    for (int j = 0; j < 3; ++j) {
      int c = tc * 3 + j;
      float v = acc[i][j] + bs[c];
      if (c < 16) out[(size_t)rr * 16 + c] = v;
      else out[(size_t)M * 16 + (size_t)rr * 32 + (c - 16)] = v;
    }
  }
}

extern "C" void kernel_launch(void* const* d_in, const int* in_sizes, int n_in,
                              void* d_out, int out_size, void* d_ws, size_t ws_size,
                              hipStream_t stream) {
  const float* x    = (const float*)d_in[0];
  const int*   ei   = (const int*)d_in[1];
  const float* ew   = (const float*)d_in[2];
  const float* W1   = (const float*)d_in[3];
  const float* b1   = (const float*)d_in[4];
  const float* W2   = (const float*)d_in[5];
  const float* b2   = (const float*)d_in[6];
  const float* fW1  = (const float*)d_in[7];
  const float* fb1  = (const float*)d_in[8];
  const float* fW2  = (const float*)d_in[9];
  const float* fb2  = (const float*)d_in[10];
  float* out = (float*)d_out;

  const int N = in_sizes[0] / N_FEAT;      // 50000 < 65536 (16-bit src pack)
  const int E = in_sizes[2];
  const int H = (N + 63) & ~63;
  const int* row = ei;
  const int* col = ei + E;

  char* ws = (char*)d_ws;
  float*              dinv = (float*)(ws + 0x000000);               // N f
  int*                off  = (int*)  (ws + 0x080000);               // N+1 i
  int*                bsum = (int*)  (ws + 0x0C0000);
  int*                bsum2= (int*)  (ws + 0x0C1000);
  short*              BF1  = (short*)(ws + 0x0C8000);               // 64KB frag-order B1
  short*              BF2  = (short*)(ws + 0x0DA000);               // 8KB frag-order B2
  unsigned long long* hist = (unsigned long long*)(ws + 0x100000);  // 8*H u64 (3.2MB)
  int*                cur  = (int*)  (ws + 0x500000);               // 8*H i (1.6MB)
  unsigned*           pairs= (unsigned*)(ws + 0x6C0000);            // E u32 (3.2MB)
  u16*                bufA = (u16*)  (ws + 0xD40000);               // N*64 bf16 (6.4MB)
  u16*                bufB = (u16*)  (ws + 0x1980000);              // N*64 bf16 (6.4MB)

  const int nbN  = (N + 255) / 256;
  const int nbE  = (E + 255) / 256;
  const int nbT  = (N + 15) / 16;          // 16-row tiles (3125)
  const int nGB  = (nbT + 3) / 4;          // GEMM blocks in fused dispatch (782)
  const int nbG  = (N + 63) / 64;
  const int nbW  = (N * 64 + 255) / 256;
  const int nH16 = NPART * H / 2;          // hist size in uint4 units
  const int nbZ  = (nH16 + 255) / 256;

  // ---- init: zero hist + weight pre-pack (one dispatch) ----
  k_init<<<nbZ + 18, 256, 0, stream>>>((uint4*)hist, nH16, W1, BF1, W2, BF2, nbZ);

  // ---- degree histogram + normalization + CSR offsets ----
  k_degcnt2<<<nbE, 256, 0, stream>>>(col, ew, hist, H, E);
  k_redscan<<<nbN, 256, 0, stream>>>(hist, H, dinv, off, bsum, N);
  k_scan2  <<<1,   256, 0, stream>>>(bsum, bsum2, nbN);
  k_scan3_initcur<<<nbN, 256, 0, stream>>>(off, bsum2, hist, H, cur, N, E);

  // ---- FUSED: xw1 = x@W1  ||  CSR fill (independent; co-scheduled) ----
  k_gemmfill<<<5 * nGB, 256, 0, stream>>>(
      x, (const short8*)BF1, bufA, N, nbT,
      row, col, ew, dinv, cur, H, pairs, E);

  // ---- layer 1 conv: h1 = relu(gather) ----
  k_gather<true><<<nbW, 256, 0, stream>>>(off, pairs, dinv, bufA, b1, bufB, N);

  // ---- layer 2: xw2 = h1@W2; h2 = gather ----
  k_mfma64<<<nbT, 64, 0, stream>>>(bufB, (const short8*)BF2, bufA, N);
  k_gather<false><<<nbW, 256, 0, stream>>>(off, pairs, dinv, bufA, b2, bufB, N);

  // ---- FC heads ----
  k_fc<<<nbG, 256, 0, stream>>>(bufB, fW1, fb1, fW2, fb2, out, N);
}